// Round 11
// baseline (79.442 us; speedup 1.0000x reference)
//
#include <hip/hip_runtime.h>

// cluster (discriminative) loss: L_var + L_dist, C=4, K=5.
// Cooperative single kernel, pixels register-resident (one 40MB read).
// R9/R10 diagnosis: the barrier was fine; the SINGLE-finisher serial reduce
// (25 cols x 4 dependent ~0.9us coherence reads while 1023 blocks sleep)
// was the ~25us tail. Fix: TREE reduction. 32 contiguous groups; each
// group-last block slab-reads its group's 32x32-float rows with ONE float4
// per thread (single latency), LDS column-sum, publish; super-last repeats
// over group results. Publish rows are 128B-line-aligned.
// Sync rules kept: atomicExch publish; hierarchical tickets (R5);
// __threadfence only in the 33 reducing blocks (R4); distributed
// per-group flags + slow s_sleep poll (R9/R10, harmless).
// Fallback: proven round-3 pipeline if coop launch fails.

constexpr int K   = 5;
constexpr int C   = 4;
constexpr int TPB = 256;
constexpr int PPT = 8;
constexpr int NB  = 1024;     // 1024*256*8 = 2^21 = HW exactly
constexpr int NG  = 32;       // groups
constexpr int GS  = 32;       // blocks per group (contiguous: g = bid>>5)
constexpr int ROW = 32;       // floats per publish row (128B line)
constexpr int TS  = 16;       // ints between ticket counters (64B)

// bar ints layout
constexpr int BAR_GT1   = 0;            // 32*16
constexpr int BAR_ST1   = 512;
constexpr int BAR_GT2   = 528;          // 32*16
constexpr int BAR_ST2   = 1040;
constexpr int BAR_FLAGS = 1056;         // 32*16
constexpr int BAR_INTS  = 1568;

__device__ __forceinline__ float wave_reduce_sum(float v) {
#pragma unroll
  for (int off = 32; off > 0; off >>= 1) v += __shfl_down(v, off, 64);
  return v;
}

// ======================= fused cooperative kernel =======================
__global__ __launch_bounds__(TPB, 4) void k_fused(
    const float* __restrict__ pred, const int* __restrict__ lab,
    const float* __restrict__ dv_p, const float* __restrict__ dd_p,
    float* __restrict__ partial, float* __restrict__ gpart,
    float* __restrict__ vpart, float* __restrict__ gv,
    float* __restrict__ fcopy, float* __restrict__ finals,
    int* __restrict__ bar, float* __restrict__ out, int HW) {
  const int tid = threadIdx.x, bid = blockIdx.x;
  const int wave = tid >> 6, lane = tid & 63;
  const int g = bid >> 5;   // contiguous groups of 32 blocks

  int* gtick1 = bar + BAR_GT1;
  int* stick1 = bar + BAR_ST1;
  int* gtick2 = bar + BAR_GT2;
  int* stick2 = bar + BAR_ST2;
  int* flags  = bar + BAR_FLAGS;

  __shared__ float red[TPB / 64][25];
  __shared__ float sm[GS][ROW];        // 4KB slab buffer (reused 4x)
  __shared__ float muS[21];
  __shared__ float smu[20];
  __shared__ float red2[TPB / 64][K];
  __shared__ int lastG, lastS, lastG2, lastS2;

  // ---------- Phase A: load ONCE into registers; per-thread stats ----------
  const long long p0 = ((long long)bid * TPB + tid) * PPT;
  float x[PPT][C];
  int labv[PPT];
  if (p0 + PPT <= HW) {
    int4 la = *reinterpret_cast<const int4*>(lab + p0);
    int4 lb = *reinterpret_cast<const int4*>(lab + p0 + 4);
    labv[0]=la.x; labv[1]=la.y; labv[2]=la.z; labv[3]=la.w;
    labv[4]=lb.x; labv[5]=lb.y; labv[6]=lb.z; labv[7]=lb.w;
#pragma unroll
    for (int c = 0; c < C; ++c) {
      const float* base = pred + (long long)c * HW + p0;
      float4 a = *reinterpret_cast<const float4*>(base);
      float4 b = *reinterpret_cast<const float4*>(base + 4);
      x[0][c]=a.x; x[1][c]=a.y; x[2][c]=a.z; x[3][c]=a.w;
      x[4][c]=b.x; x[5][c]=b.y; x[6][c]=b.z; x[7][c]=b.w;
    }
  } else {
#pragma unroll
    for (int p = 0; p < PPT; ++p) {
      if (p0 + p < HW) {
        labv[p] = lab[p0 + p];
#pragma unroll
        for (int c = 0; c < C; ++c) x[p][c] = pred[(long long)c * HW + p0 + p];
      } else {
        labv[p] = -1;
#pragma unroll
        for (int c = 0; c < C; ++c) x[p][c] = 0.f;
      }
    }
  }

  float cnt[K] = {0.f, 0.f, 0.f, 0.f, 0.f};
  float sum[K][C] = {};
#pragma unroll
  for (int p = 0; p < PPT; ++p) {
    const int l = labv[p];
#pragma unroll
    for (int k = 0; k < K; ++k) {
      const float m = (l == k) ? 1.0f : 0.0f;
      cnt[k] += m;
#pragma unroll
      for (int c = 0; c < C; ++c) sum[k][c] = fmaf(m, x[p][c], sum[k][c]);
    }
  }

#pragma unroll
  for (int j = 0; j < 25; ++j) {
    float v = (j < K) ? cnt[j] : sum[(j - K) >> 2][(j - K) & 3];
    v = wave_reduce_sum(v);
    if (lane == 0) red[wave][j] = v;
  }
  __syncthreads();
  if (tid < 25) {
    float t = red[0][tid] + red[1][tid] + red[2][tid] + red[3][tid];
    atomicExch(&partial[bid * ROW + tid], t);   // one 128B line per block
  }
  __syncthreads();  // drains vmcnt(0): publishes complete before arrival

  // ---------- group arrival; group-last reduces its 32x32 slab ----------
  if (tid == 0) lastG = (atomicAdd(&gtick1[g * TS], 1) == GS - 1) ? 1 : 0;
  __syncthreads();
  if (lastG) {
    __threadfence();  // acquire (32 blocks total): invalidate stale lines
    const float4* src = reinterpret_cast<const float4*>(partial +
                                                        (long long)g * GS * ROW);
    float4 v = src[tid];                         // ONE load latency
    reinterpret_cast<float4*>(&sm[0][0])[tid] = v;
    __syncthreads();
    if (tid < 25) {
      float s = 0.f;
#pragma unroll
      for (int r = 0; r < GS; ++r) s += sm[r][tid];
      atomicExch(&gpart[g * ROW + tid], s);
    }
    __syncthreads();  // drain
    if (tid == 0) lastS = (atomicAdd(stick1, 1) == NG - 1) ? 1 : 0;
    __syncthreads();
    // ---------- super-last: centroids + L_dist, replicate, flags ----------
    if (lastS) {
      __threadfence();  // acquire (1 block)
      const float4* s2 = reinterpret_cast<const float4*>(gpart);
      float4 w = s2[tid];
      __syncthreads();  // sm reuse safe: previous readers done
      reinterpret_cast<float4*>(&sm[0][0])[tid] = w;
      __syncthreads();
      if (tid < 25) {
        float s = 0.f;
#pragma unroll
        for (int r = 0; r < NG; ++r) s += sm[r][tid];
        red[0][tid] = s;  // tot
      }
      __syncthreads();
      if (tid == 0) {
        const float dd = dd_p[0];
        float cntv[K], mu[K][C];
#pragma unroll
        for (int k = 0; k < K; ++k) {
          cntv[k] = red[0][k];
          const float inv = 1.0f / fmaxf(cntv[k], 1.0f);
#pragma unroll
          for (int c = 0; c < C; ++c) mu[k][c] = red[0][K + k * C + c] * inv;
        }
        float ld = 0.f;
#pragma unroll
        for (int a = 0; a < K; ++a) {
#pragma unroll
          for (int b = 0; b < K; ++b) {
            if (a == b) continue;
            float csq = 0.f;
#pragma unroll
            for (int c = 0; c < C; ++c) {
              const float d = mu[a][c] - mu[b][c];
              csq = fmaf(d, d, csq);
            }
            const float cd = csq > 0.f ? sqrtf(csq) : 0.f;
            const float dh = fmaxf(dd - cd, 0.f);
            ld = fmaf(dh, dh, ld);
          }
        }
        ld *= 1.0f / (float)(K * (K - 1));
#pragma unroll
        for (int k = 0; k < K; ++k) atomicExch(&finals[k], cntv[k]);
        atomicExch(&finals[25], ld);
#pragma unroll
        for (int k = 0; k < K; ++k)
#pragma unroll
          for (int c = 0; c < C; ++c) muS[k * C + c] = mu[k][c];
      }
      __syncthreads();
      // replicate mu into per-group 128B rows
      for (int idx = tid; idx < NG * 20; idx += TPB) {
        const int gg = idx / 20, j = idx % 20;
        atomicExch(&fcopy[gg * ROW + j], muS[j]);
      }
      __syncthreads();  // drain copies before flags
      if (tid < NG) atomicExch(&flags[tid * TS], 1);
    }
  }

  // ---------- wait on per-group flag (32 pollers/line, slow poll) ----------
  if (tid == 0) {
    while (__hip_atomic_load(&flags[g * TS], __ATOMIC_RELAXED,
                             __HIP_MEMORY_SCOPE_AGENT) == 0)
      __builtin_amdgcn_s_sleep(16);
  }
  __syncthreads();

  // ---------- Phase C: hinge on REGISTER-resident pixels ----------
  if (tid < 20)
    smu[tid] = __hip_atomic_load(&fcopy[g * ROW + tid], __ATOMIC_RELAXED,
                                 __HIP_MEMORY_SCOPE_AGENT);
  __syncthreads();
  const float dv = dv_p[0];

  float vs[K] = {};
#pragma unroll
  for (int p = 0; p < PPT; ++p) {
    const int l = labv[p];
    if (l >= 0) {
      const float d0 = smu[l * C + 0] - x[p][0];
      const float d1 = smu[l * C + 1] - x[p][1];
      const float d2 = smu[l * C + 2] - x[p][2];
      const float d3 = smu[l * C + 3] - x[p][3];
      float dsq = d0 * d0;
      dsq = fmaf(d1, d1, dsq);
      dsq = fmaf(d2, d2, dsq);
      dsq = fmaf(d3, d3, dsq);
      const float dn = dsq > 0.f ? sqrtf(dsq) : 0.f;
      const float h  = fmaxf(dn - dv, 0.f);
      const float var = h * h;
#pragma unroll
      for (int k = 0; k < K; ++k) vs[k] += (l == k) ? var : 0.f;
    }
  }

#pragma unroll
  for (int j = 0; j < K; ++j) {
    float v = wave_reduce_sum(vs[j]);
    if (lane == 0) red2[wave][j] = v;
  }
  __syncthreads();
  if (tid < K) {
    float t = red2[0][tid] + red2[1][tid] + red2[2][tid] + red2[3][tid];
    atomicExch(&vpart[bid * ROW + tid], t);
  }
  __syncthreads();  // drain

  // ---------- tree-reduce L_var sums; super-last writes out ----------
  if (tid == 0) lastG2 = (atomicAdd(&gtick2[g * TS], 1) == GS - 1) ? 1 : 0;
  __syncthreads();
  if (!lastG2) return;

  __threadfence();  // acquire (32 blocks)
  {
    const float4* src = reinterpret_cast<const float4*>(vpart +
                                                        (long long)g * GS * ROW);
    float4 v = src[tid];
    __syncthreads();  // sm reuse safe
    reinterpret_cast<float4*>(&sm[0][0])[tid] = v;
    __syncthreads();
    if (tid < K) {
      float s = 0.f;
#pragma unroll
      for (int r = 0; r < GS; ++r) s += sm[r][tid];
      atomicExch(&gv[g * ROW + tid], s);
    }
    __syncthreads();  // drain
    if (tid == 0) lastS2 = (atomicAdd(stick2, 1) == NG - 1) ? 1 : 0;
    __syncthreads();
  }
  if (!lastS2) return;

  __threadfence();  // acquire (1 block)
  {
    const float4* s2 = reinterpret_cast<const float4*>(gv);
    float4 w = s2[tid];
    __syncthreads();
    reinterpret_cast<float4*>(&sm[0][0])[tid] = w;
    __syncthreads();
    if (tid == 0) {
      float lvar = 0.f;
#pragma unroll
      for (int k = 0; k < K; ++k) {
        float s = 0.f;
#pragma unroll
        for (int r = 0; r < NG; ++r) s += sm[r][k];
        const float cv = __hip_atomic_load(&finals[k], __ATOMIC_RELAXED,
                                           __HIP_MEMORY_SCOPE_AGENT);
        lvar += s / fmaxf(cv, 1.0f);
      }
      lvar *= 1.0f / (float)K;
      const float ld = __hip_atomic_load(&finals[25], __ATOMIC_RELAXED,
                                         __HIP_MEMORY_SCOPE_AGENT);
      out[0] = lvar + ld;
    }
  }
}

// ======================= fallback: proven round-3 pipeline =======================
constexpr int RED_TPB = 1024;

__device__ __forceinline__ float wave_col_sum1024(const float* __restrict__ colp,
                                                  int lane) {
  const float4* p4 = reinterpret_cast<const float4*>(colp);
  float4 a0 = p4[lane];
  float4 a1 = p4[lane + 64];
  float4 a2 = p4[lane + 128];
  float4 a3 = p4[lane + 192];
  float s = (a0.x + a0.y) + (a0.z + a0.w);
  s += (a1.x + a1.y) + (a1.z + a1.w);
  s += (a2.x + a2.y) + (a2.z + a2.w);
  s += (a3.x + a3.y) + (a3.z + a3.w);
  return wave_reduce_sum(s);
}

__global__ __launch_bounds__(TPB) void k_stats(
    const float* __restrict__ pred, const int* __restrict__ lab,
    float* __restrict__ partial, int HW) {
  const int tid = threadIdx.x;
  float cnt[K] = {0.f, 0.f, 0.f, 0.f, 0.f};
  float sum[K][C] = {};
  const long long p0 = ((long long)blockIdx.x * TPB + tid) * PPT;
  if (p0 + PPT <= HW) {
    int4 la = *reinterpret_cast<const int4*>(lab + p0);
    int4 lb = *reinterpret_cast<const int4*>(lab + p0 + 4);
    int labv[PPT] = {la.x, la.y, la.z, la.w, lb.x, lb.y, lb.z, lb.w};
    float x[PPT][C];
#pragma unroll
    for (int c = 0; c < C; ++c) {
      const float* base = pred + (long long)c * HW + p0;
      float4 a = *reinterpret_cast<const float4*>(base);
      float4 b = *reinterpret_cast<const float4*>(base + 4);
      x[0][c]=a.x; x[1][c]=a.y; x[2][c]=a.z; x[3][c]=a.w;
      x[4][c]=b.x; x[5][c]=b.y; x[6][c]=b.z; x[7][c]=b.w;
    }
#pragma unroll
    for (int p = 0; p < PPT; ++p) {
      const int l = labv[p];
#pragma unroll
      for (int k = 0; k < K; ++k) {
        const float m = (l == k) ? 1.0f : 0.0f;
        cnt[k] += m;
#pragma unroll
        for (int c = 0; c < C; ++c) sum[k][c] = fmaf(m, x[p][c], sum[k][c]);
      }
    }
  }
  __shared__ float red[TPB / 64][25];
  const int wave = tid >> 6, lane = tid & 63;
#pragma unroll
  for (int j = 0; j < 25; ++j) {
    float v = (j < K) ? cnt[j] : sum[(j - K) >> 2][(j - K) & 3];
    v = wave_reduce_sum(v);
    if (lane == 0) red[wave][j] = v;
  }
  __syncthreads();
  if (tid < 25) {
    float t = red[0][tid] + red[1][tid] + red[2][tid] + red[3][tid];
    partial[tid * NB + blockIdx.x] = t;
  }
}

__global__ __launch_bounds__(RED_TPB) void k_centroids(
    const float* __restrict__ partial, const float* __restrict__ dd_p,
    float* __restrict__ finals) {
  __shared__ float tot[25];
  const int tid = threadIdx.x, wave = tid >> 6, lane = tid & 63;
  for (int col = wave; col < 25; col += RED_TPB / 64) {
    float v = wave_col_sum1024(partial + col * NB, lane);
    if (lane == 0) tot[col] = v;
  }
  __syncthreads();
  if (tid == 0) {
    const float dd = dd_p[0];
    float cnt[K], mu[K][C];
#pragma unroll
    for (int k = 0; k < K; ++k) {
      cnt[k] = tot[k];
      const float inv = 1.0f / fmaxf(cnt[k], 1.0f);
#pragma unroll
      for (int c = 0; c < C; ++c) mu[k][c] = tot[K + k * C + c] * inv;
    }
    float ld = 0.f;
#pragma unroll
    for (int a = 0; a < K; ++a)
#pragma unroll
      for (int b = 0; b < K; ++b) {
        if (a == b) continue;
        float csq = 0.f;
#pragma unroll
        for (int c = 0; c < C; ++c) {
          const float d = mu[a][c] - mu[b][c];
          csq = fmaf(d, d, csq);
        }
        const float cd = csq > 0.f ? sqrtf(csq) : 0.f;
        const float dh = fmaxf(dd - cd, 0.f);
        ld = fmaf(dh, dh, ld);
      }
    ld *= 1.0f / (float)(K * (K - 1));
#pragma unroll
    for (int k = 0; k < K; ++k) finals[k] = cnt[k];
#pragma unroll
    for (int k = 0; k < K; ++k)
#pragma unroll
      for (int c = 0; c < C; ++c) finals[K + k * C + c] = mu[k][c];
    finals[25] = ld;
  }
}

__global__ __launch_bounds__(TPB) void k_var(
    const float* __restrict__ pred, const int* __restrict__ lab,
    const float* __restrict__ finals, const float* __restrict__ dv_p,
    float* __restrict__ vpartial, int HW) {
  __shared__ __align__(16) float smu[K * C];
  if (threadIdx.x < K * C) smu[threadIdx.x] = finals[K + threadIdx.x];
  __syncthreads();
  const float dv = dv_p[0];
  const int tid = threadIdx.x;
  float vs[K] = {};
  const long long p0 = ((long long)blockIdx.x * TPB + tid) * PPT;
  if (p0 + PPT <= HW) {
    int4 la = *reinterpret_cast<const int4*>(lab + p0);
    int4 lb = *reinterpret_cast<const int4*>(lab + p0 + 4);
    int labv[PPT] = {la.x, la.y, la.z, la.w, lb.x, lb.y, lb.z, lb.w};
    float x[PPT][C];
#pragma unroll
    for (int c = 0; c < C; ++c) {
      const float* base = pred + (long long)c * HW + p0;
      float4 a = *reinterpret_cast<const float4*>(base);
      float4 b = *reinterpret_cast<const float4*>(base + 4);
      x[0][c]=a.x; x[1][c]=a.y; x[2][c]=a.z; x[3][c]=a.w;
      x[4][c]=b.x; x[5][c]=b.y; x[6][c]=b.z; x[7][c]=b.w;
    }
#pragma unroll
    for (int p = 0; p < PPT; ++p) {
      const int l = labv[p];
      const float4 mu = *reinterpret_cast<const float4*>(&smu[l * C]);
      const float d0 = mu.x - x[p][0];
      const float d1 = mu.y - x[p][1];
      const float d2 = mu.z - x[p][2];
      const float d3 = mu.w - x[p][3];
      float dsq = d0 * d0;
      dsq = fmaf(d1, d1, dsq);
      dsq = fmaf(d2, d2, dsq);
      dsq = fmaf(d3, d3, dsq);
      const float dn = dsq > 0.f ? sqrtf(dsq) : 0.f;
      const float h  = fmaxf(dn - dv, 0.f);
      const float var = h * h;
#pragma unroll
      for (int k = 0; k < K; ++k) vs[k] += (l == k) ? var : 0.f;
    }
  }
  __shared__ float red[TPB / 64][K];
  const int wave = tid >> 6, lane = tid & 63;
#pragma unroll
  for (int j = 0; j < K; ++j) {
    float v = wave_reduce_sum(vs[j]);
    if (lane == 0) red[wave][j] = v;
  }
  __syncthreads();
  if (tid < K) {
    float t = red[0][tid] + red[1][tid] + red[2][tid] + red[3][tid];
    vpartial[tid * NB + blockIdx.x] = t;
  }
}

__global__ __launch_bounds__(RED_TPB) void k_final(
    const float* __restrict__ vpartial, const float* __restrict__ finals,
    float* __restrict__ out) {
  __shared__ float tot[K];
  const int tid = threadIdx.x, wave = tid >> 6, lane = tid & 63;
  if (wave < K) {
    float v = wave_col_sum1024(vpartial + wave * NB, lane);
    if (lane == 0) tot[wave] = v;
  }
  __syncthreads();
  if (tid == 0) {
    float lvar = 0.f;
#pragma unroll
    for (int k = 0; k < K; ++k) lvar += tot[k] / fmaxf(finals[k], 1.0f);
    lvar *= 1.0f / (float)K;
    out[0] = lvar + finals[25];
  }
}

extern "C" void kernel_launch(void* const* d_in, const int* in_sizes, int n_in,
                              void* d_out, int out_size, void* d_ws, size_t ws_size,
                              hipStream_t stream) {
  const float* pred = (const float*)d_in[0];
  const int*   lab  = (const int*)d_in[1];
  const float* dv   = (const float*)d_in[2];
  const float* dd   = (const float*)d_in[3];
  float*       out  = (float*)d_out;

  const int HW = in_sizes[1];  // 1024*2048 = 2^21

  float* ws      = (float*)d_ws;
  float* partial = ws;                          // NB*ROW = 32768 floats
  float* vpart   = partial + NB * ROW;          // NB*ROW
  float* gpart   = vpart + NB * ROW;            // NG*ROW = 1024
  float* gv      = gpart + NG * ROW;            // NG*ROW
  float* fcopy   = gv + NG * ROW;               // NG*ROW
  float* finals  = fcopy + NG * ROW;            // 32
  int*   bar     = (int*)(finals + 32);         // BAR_INTS

  hipMemsetAsync(bar, 0, BAR_INTS * sizeof(int), stream);

  void* args[] = {(void*)&pred, (void*)&lab, (void*)&dv, (void*)&dd,
                  (void*)&partial, (void*)&gpart, (void*)&vpart, (void*)&gv,
                  (void*)&fcopy, (void*)&finals, (void*)&bar, (void*)&out,
                  (void*)&HW};
  hipError_t err = hipLaunchCooperativeKernel(
      (const void*)k_fused, dim3(NB), dim3(TPB), args, 0, stream);

  if (err != hipSuccess) {
    // fallback: proven round-3 pipeline (33.3 us). Column-major partials.
    k_stats    <<<NB, TPB, 0, stream>>>(pred, lab, partial, HW);
    k_centroids<<<1,  RED_TPB, 0, stream>>>(partial, dd, finals);
    k_var      <<<NB, TPB, 0, stream>>>(pred, lab, finals, dv, vpart, HW);
    k_final    <<<1,  RED_TPB, 0, stream>>>(vpart, finals, out);
  }
}